// Round 11
// baseline (161.910 us; speedup 1.0000x reference)
//
#include <hip/hip_runtime.h>
#include <hip/hip_bf16.h>

#define B_ 4
#define S_ 4
#define C_ 4
#define L_ 512
#define E_ 64
#define A_ 32
#define H_ 8
#define HA_ 256      // H_*A_
#define KREAL 2052   // S_*L_ + C_
#define KP 2112      // padded to 33*64
#define NKT 33
#define SCALE 0.17677669529663687f   // 1/sqrt(32)
#define SCALE2 0.25503486321392056f  // log2(e)/sqrt(32)  (Q pre-scale, exp2 domain)
#define NEGINF (-__builtin_inff())

using bf16  = __bf16;
using bf16x8 = __attribute__((ext_vector_type(8))) __bf16;
using f32x4  = __attribute__((ext_vector_type(4))) float;

// workspace layout (byte offsets)
#define OFF_QS    0ull            // bf16 [B][S][H][L][A]  (pre-scaled by SCALE2)
#define OFF_KALL  4194304ull      // bf16 [B][H][KP][A]
#define OFF_VT    8519680ull      // bf16 [B][H][A][KP]
#define OFF_OUTS  12845056ull     // bf16 [B][S][L][HA]
#define OFF_OUTC  17039360ull     // f32  [B][C][HA]
// total ~17.1 MB

// ---------------------------------------------------------------------------
// Ballot-based dtype detection: no barriers, no atomics, wave-uniform.
// Each lane reads x0[lane]; f32 words have mantissa noise in bits 7..14
// (~75% wild), bf16 low-halves have sane exponents there (~0%). Thresh 16/64.
// ---------------------------------------------------------------------------
__device__ __forceinline__ bool detect_f32_fast(const unsigned int* __restrict__ x0)
{
  unsigned v = x0[threadIdx.x & 63];
  int e = (int)((v >> 7) & 0xFF);
  bool weird = (e == 0xFF || e < 0x60 || e > 0x9F);
  unsigned long long m = __ballot(weird);
  return __builtin_popcountll(m) > 16;
}

// dual-dtype loads
__device__ __forceinline__ bf16x8 ld8(const void* p, size_t idx, bool isf32) {
  if (isf32) {
    const float* f = (const float*)p + idx;
    float4 lo = *(const float4*)f;
    float4 hi = *(const float4*)(f + 4);
    bf16x8 v;
    v[0] = (bf16)lo.x; v[1] = (bf16)lo.y; v[2] = (bf16)lo.z; v[3] = (bf16)lo.w;
    v[4] = (bf16)hi.x; v[5] = (bf16)hi.y; v[6] = (bf16)hi.z; v[7] = (bf16)hi.w;
    return v;
  }
  return *(const bf16x8*)((const bf16*)p + idx);
}
__device__ __forceinline__ float ldf(const void* p, size_t idx, bool isf32) {
  return isf32 ? ((const float*)p)[idx] : (float)((const bf16*)p)[idx];
}

// ---------------------------------------------------------------------------
// Kernel 1: QKV projections (MFMA), raw dual-dtype inputs.
// 1024 seq blocks (b,s,h,lc8 of 64 rows; h=bid&7 for XCD locality) +
// 128 const blocks. 4.5 blocks/CU for latency hiding.
// Decode: h bits0-2, lc8 bits3-5, s bits6-7, b bits8-9 (verified complete).
// ---------------------------------------------------------------------------
__global__ __launch_bounds__(256) void proj_kernel(
    const void* __restrict__ xq, const void* __restrict__ xk, const void* __restrict__ xv,
    const void* __restrict__ kc_in, const void* __restrict__ vc_in,
    const void* __restrict__ wq, const void* __restrict__ wk, const void* __restrict__ wv,
    const void* __restrict__ wkc, const void* __restrict__ wvc,
    bf16* __restrict__ qs, bf16* __restrict__ kall, bf16* __restrict__ vt)
{
  bool isf32 = detect_f32_fast((const unsigned int*)xq);
  int bid = blockIdx.x;
  int tid = threadIdx.x;
  if (bid < 1024) {
    int h = bid & 7, lc8 = (bid >> 3) & 7, s = (bid >> 6) & 3, b = (bid >> 8) & 3;
    __shared__ bf16 wt[3 * 32 * 72];      // W^T [a][e], stride 72
    __shared__ bf16 v_lds[32 * 72];       // V^T tile [a][l_local(64)], stride 72
    {
      size_t hb = (size_t)(s * H_ + h) * E_ * A_;
      int e = tid >> 2, ac = tid & 3;
      bf16x8 vq = ld8(wq, hb + e * 32 + ac * 8, isf32);
      bf16x8 vk = ld8(wk, hb + e * 32 + ac * 8, isf32);
      bf16x8 vv = ld8(wv, hb + e * 32 + ac * 8, isf32);
#pragma unroll
      for (int j = 0; j < 8; ++j) {
        int a = ac * 8 + j;
        wt[0 * 2304 + a * 72 + e] = vq[j];
        wt[1 * 2304 + a * 72 + e] = vk[j];
        wt[2 * 2304 + a * 72 + e] = vv[j];
      }
    }
    __syncthreads();
    int lane = tid & 63, wave = tid >> 6;
    int quad = lane >> 4, r = lane & 15;
    const size_t xbase = (size_t)(b * S_ + s) * L_ * E_;
    const size_t qsb   = (size_t)((b * S_ + s) * H_ + h) * L_ * A_;
    const size_t kab   = (size_t)(b * H_ + h) * KP * A_;
    const size_t vtb   = (size_t)(b * H_ + h) * A_ * KP;
    int lloc0 = wave * 16;                 // local row within 64-chunk
    int row0 = lc8 * 64 + lloc0;           // row within L
    size_t rowoff = xbase + (size_t)(row0 + r) * E_ + quad * 8;
    bf16x8 aq0 = ld8(xq, rowoff, isf32);
    bf16x8 aq1 = ld8(xq, rowoff + 32, isf32);
    bf16x8 ak0 = ld8(xk, rowoff, isf32);
    bf16x8 ak1 = ld8(xk, rowoff + 32, isf32);
    bf16x8 av0 = ld8(xv, rowoff, isf32);
    bf16x8 av1 = ld8(xv, rowoff + 32, isf32);
#pragma unroll
    for (int nt = 0; nt < 2; ++nt) {
      bf16x8 bq0 = *(const bf16x8*)&wt[(nt * 16 + r) * 72 + 0 + quad * 8];
      bf16x8 bq1 = *(const bf16x8*)&wt[(nt * 16 + r) * 72 + 32 + quad * 8];
      bf16x8 bk0 = *(const bf16x8*)&wt[2304 + (nt * 16 + r) * 72 + 0 + quad * 8];
      bf16x8 bk1 = *(const bf16x8*)&wt[2304 + (nt * 16 + r) * 72 + 32 + quad * 8];
      bf16x8 bv0 = *(const bf16x8*)&wt[4608 + (nt * 16 + r) * 72 + 0 + quad * 8];
      bf16x8 bv1 = *(const bf16x8*)&wt[4608 + (nt * 16 + r) * 72 + 32 + quad * 8];
      f32x4 accq = {0.f,0.f,0.f,0.f}, acck = {0.f,0.f,0.f,0.f}, accv = {0.f,0.f,0.f,0.f};
      accq = __builtin_amdgcn_mfma_f32_16x16x32_bf16(aq0, bq0, accq, 0,0,0);
      accq = __builtin_amdgcn_mfma_f32_16x16x32_bf16(aq1, bq1, accq, 0,0,0);
      acck = __builtin_amdgcn_mfma_f32_16x16x32_bf16(ak0, bk0, acck, 0,0,0);
      acck = __builtin_amdgcn_mfma_f32_16x16x32_bf16(ak1, bk1, acck, 0,0,0);
      accv = __builtin_amdgcn_mfma_f32_16x16x32_bf16(av0, bv0, accv, 0,0,0);
      accv = __builtin_amdgcn_mfma_f32_16x16x32_bf16(av1, bv1, accv, 0,0,0);
#pragma unroll
      for (int reg = 0; reg < 4; ++reg) {
        int l = row0 + quad * 4 + reg;
        int a = nt * 16 + r;
        qs[qsb + (size_t)l * A_ + a]              = (bf16)(accq[reg] * SCALE2);
        kall[kab + (size_t)(s * L_ + l) * A_ + a] = (bf16)acck[reg];
        v_lds[a * 72 + lloc0 + quad * 4 + reg]    = (bf16)accv[reg];
      }
    }
    __syncthreads();
    {  // coalesced store of V^T tile: 32 rows x 64 elems
      int a = tid >> 3, c8 = tid & 7;
      *(bf16x8*)&vt[vtb + (size_t)a * KP + s * L_ + lc8 * 64 + c8 * 8] =
          *(const bf16x8*)&v_lds[a * 72 + c8 * 8];
    }
  } else {
    int cid = bid - 1024;
    int b = cid >> 5, c = (cid >> 3) & 3, h = cid & 7;
    if (tid < 32) {
      int a = tid;
      float kacc = 0.f, vacc = 0.f;
#pragma unroll 8
      for (int e = 0; e < E_; ++e) {
        float xke = ldf(kc_in, (b * C_ + c) * E_ + e, isf32);
        float xve = ldf(vc_in, (b * C_ + c) * E_ + e, isf32);
        float wke = ldf(wkc, ((size_t)(c * H_ + h) * E_ + e) * A_ + a, isf32);
        float wve = ldf(wvc, ((size_t)(c * H_ + h) * E_ + e) * A_ + a, isf32);
        kacc += xke * wke;
        vacc += xve * wve;
      }
      kall[((size_t)(b * H_ + h) * KP + (S_ * L_ + c)) * A_ + a] = (bf16)kacc;
      vt[((size_t)(b * H_ + h) * A_ + a) * KP + (S_ * L_ + c)]   = (bf16)vacc;
    }
    if (c == 0) {  // zero pad keys 2052..2111
      for (int idx = tid; idx < 60 * 32; idx += 256) {
        int k = KREAL + (idx >> 5), a = idx & 31;
        kall[((size_t)(b * H_ + h) * KP + k) * A_ + a] = (bf16)0.f;
        vt[((size_t)(b * H_ + h) * A_ + a) * KP + k]   = (bf16)0.f;
      }
    }
  }
}

// ---------------------------------------------------------------------------
// Kernel 2: flash attention (blocks 0..1023, R7/R9 validated geometry) +
// constant-query attention (blocks 1024..1151).
// ---------------------------------------------------------------------------
__global__ __launch_bounds__(256) void attn_kernel(
    const bf16* __restrict__ qs, const bf16* __restrict__ kall, const bf16* __restrict__ vt,
    const int* __restrict__ maskp, bf16* __restrict__ outs,
    const void* __restrict__ qc_raw, const void* __restrict__ wqc_raw,
    const unsigned int* __restrict__ x0, float* __restrict__ outc)
{
  __shared__ __attribute__((aligned(16))) bf16 kt_lds[64 * 40];     // 5120 B
  __shared__ __attribute__((aligned(16))) bf16 vt_lds[32 * 72];     // 4608 B
  __shared__ __attribute__((aligned(16))) bf16 p_lds[4 * 16 * 72];  // 9216 B
  int bid = blockIdx.x, tid = threadIdx.x;
  int lane = tid & 63, wave = tid >> 6, quad = lane >> 4, r = lane & 15;
  if (bid < 1024) {
    int h = bid & 7;
    int q0 = (bid >> 3) & 7;
    int s = (bid >> 6) & 3;
    int b = (bid >> 8) & 3;
    int base = (q0 + 2 * (b >> 1)) & 7;
    int qt = (b & 1) ? 7 - base : base;
    bool causal = (*maskp != 0);
    int wrow = qt * 64 + wave * 16;
    int lrow = wrow + r;
    int blockmax = qt * 64 + 63;

    const size_t qsb = (size_t)((b * S_ + s) * H_ + h) * L_ * A_;
    bf16x8 aq = *(const bf16x8*)&qs[qsb + (size_t)(wrow + r) * A_ + quad * 8];

    f32x4 o[2];
    { f32x4 z = {0.f,0.f,0.f,0.f}; o[0] = z; o[1] = z; }
    float l_run = 0.f;

    const size_t kbase = (size_t)(b * H_ + h) * KP * A_;
    const size_t vbase = (size_t)(b * H_ + h) * A_ * KP;
    const int pbase = wave * 16 * 72;

#pragma unroll 1
    for (int kt = 0; kt < NKT; ++kt) {
      int kmod = (kt & 7) * 64;
      if (causal && kt < 32 && kmod > blockmax) continue;   // block-level skip
      __syncthreads();
      {
        int krow = tid >> 2, c4 = tid & 3;
        *(bf16x8*)&kt_lds[krow * 40 + c4 * 8] =
            *(const bf16x8*)&kall[kbase + (size_t)(kt * 64 + krow) * A_ + c4 * 8];
        int a8 = tid >> 3, c8 = tid & 7;
        *(bf16x8*)&vt_lds[a8 * 72 + c8 * 8] =
            *(const bf16x8*)&vt[vbase + (size_t)a8 * KP + kt * 64 + c8 * 8];
      }
      __syncthreads();
      if (causal && kt < 32 && kmod >= wrow + 16) continue; // wave-level skip
      bool fullv = (kt < 32) && (!causal || kmod + 63 <= wrow);

      f32x4 sf[4];
#pragma unroll
      for (int kg = 0; kg < 4; ++kg) {
        bf16x8 ka = *(const bf16x8*)&kt_lds[(kg * 16 + r) * 40 + quad * 8];
        f32x4 z = {0.f,0.f,0.f,0.f};
        sf[kg] = __builtin_amdgcn_mfma_f32_16x16x32_bf16(ka, aq, z, 0,0,0);
      }
      if (!fullv) {
        int thresh = (kt < 32) ? (lrow - kmod) : 3;
#pragma unroll
        for (int kg = 0; kg < 4; ++kg)
#pragma unroll
          for (int reg = 0; reg < 4; ++reg)
            if (kg * 16 + quad * 4 + reg > thresh) sf[kg][reg] = NEGINF;
      }
      // scale-free softmax: p = 2^s2 (uniform scale cancels in o/l)
      float psum = 0.f;
#pragma unroll
      for (int kg = 0; kg < 4; ++kg) {
        float p0 = exp2f(sf[kg][0]);
        float p1 = exp2f(sf[kg][1]);
        float p2 = exp2f(sf[kg][2]);
        float p3 = exp2f(sf[kg][3]);
        psum += (p0 + p1) + (p2 + p3);
        union { bf16 hh[4]; uint2 u2; } pk;
        pk.hh[0] = (bf16)p0; pk.hh[1] = (bf16)p1; pk.hh[2] = (bf16)p2; pk.hh[3] = (bf16)p3;
        *(uint2*)&p_lds[pbase + r * 72 + kg * 16 + quad * 4] = pk.u2;
      }
      psum += __shfl_xor(psum, 16);
      psum += __shfl_xor(psum, 32);
      l_run += psum;
#pragma unroll
      for (int kc2 = 0; kc2 < 2; ++kc2) {
        bf16x8 ap = *(const bf16x8*)&p_lds[pbase + r * 72 + kc2 * 32 + quad * 8];
#pragma unroll
        for (int nt = 0; nt < 2; ++nt) {
          bf16x8 bv = *(const bf16x8*)&vt_lds[(nt * 16 + r) * 72 + kc2 * 32 + quad * 8];
          o[nt] = __builtin_amdgcn_mfma_f32_16x16x32_bf16(ap, bv, o[nt], 0,0,0);
        }
      }
    }
    const size_t obase = (size_t)(b * S_ + s) * L_ * HA_;
#pragma unroll
    for (int reg = 0; reg < 4; ++reg) {
      float lo = __shfl(l_run, (lane & 48) | (quad * 4 + reg));
      int orow = wrow + quad * 4 + reg;
#pragma unroll
      for (int nt = 0; nt < 2; ++nt) {
        int f = h * A_ + nt * 16 + r;
        outs[obase + (size_t)orow * HA_ + f] = (bf16)(o[nt][reg] / lo);
      }
    }
  } else {
    // ---- constant-query attention: blocks 1024..1151 = (b,c,h), raw inputs --
    bool isf32 = detect_f32_fast(x0);
    float* parr  = (float*)p_lds;              // 8448 B <= 9216 ok
    float* qsh   = (float*)kt_lds;             // [32]
    float* red   = (float*)kt_lds + 64;        // [8]
    float* opart = (float*)kt_lds + 128;       // [32*9] <= 5120 B ok
    int cid = bid - 1024;
    int b = cid >> 5, c = (cid >> 3) & 3, h = cid & 7;
    if (tid < 32) {
      float acc = 0.f;
#pragma unroll 8
      for (int e = 0; e < E_; ++e)
        acc += ldf(qc_raw, (b * C_ + c) * E_ + e, isf32) *
               ldf(wqc_raw, ((size_t)(c * H_ + h) * E_ + e) * A_ + tid, isf32);
      qsh[tid] = acc * SCALE;
    }
    if (tid >= 192 && tid < 192 + (KP - KREAL)) parr[KREAL + tid - 192] = 0.f;
    __syncthreads();
    const size_t kbase = (size_t)(b * H_ + h) * KP * A_;
    float lmax = -1e30f;
#pragma unroll 1
    for (int j = 0; j < 9; ++j) {
      int k = tid + j * 256;
      if (k < KREAL) {
        bf16x8 k0 = *(const bf16x8*)&kall[kbase + (size_t)k * A_ + 0];
        bf16x8 k1 = *(const bf16x8*)&kall[kbase + (size_t)k * A_ + 8];
        bf16x8 k2 = *(const bf16x8*)&kall[kbase + (size_t)k * A_ + 16];
        bf16x8 k3 = *(const bf16x8*)&kall[kbase + (size_t)k * A_ + 24];
        float d = 0.f;
#pragma unroll
        for (int i = 0; i < 8; ++i) {
          d += qsh[i]      * (float)k0[i];
          d += qsh[8 + i]  * (float)k1[i];
          d += qsh[16 + i] * (float)k2[i];
          d += qsh[24 + i] * (float)k3[i];
        }
        parr[k] = d;
        lmax = fmaxf(lmax, d);
      }
    }
#pragma unroll
    for (int dlt = 1; dlt < 64; dlt <<= 1) lmax = fmaxf(lmax, __shfl_xor(lmax, dlt));
    if (lane == 0) red[wave] = lmax;
    __syncthreads();
    float bmax = fmaxf(fmaxf(red[0], red[1]), fmaxf(red[2], red[3]));
    float lsum = 0.f;
#pragma unroll 1
    for (int j = 0; j < 9; ++j) {
      int k = tid + j * 256;
      if (k < KREAL) {
        float p = __expf(parr[k] - bmax);
        parr[k] = p;
        lsum += p;
      }
    }
#pragma unroll
    for (int dlt = 1; dlt < 64; dlt <<= 1) lsum += __shfl_xor(lsum, dlt);
    if (lane == 0) red[4 + wave] = lsum;
    __syncthreads();
    float bsum = (red[4] + red[5]) + (red[6] + red[7]);
    int a = tid >> 3, ch = tid & 7;
    const size_t vbase = (size_t)(b * H_ + h) * A_ * KP + (size_t)a * KP;
    float acc = 0.f;
#pragma unroll 1
    for (int j = 0; j < 33; ++j) {
      int kb = ch * 8 + j * 64;
      bf16x8 vv = *(const bf16x8*)&vt[vbase + kb];
      float4 p0 = *(float4*)&parr[kb];
      float4 p1 = *(float4*)&parr[kb + 4];
      acc += p0.x * (float)vv[0] + p0.y * (float)vv[1] + p0.z * (float)vv[2] + p0.w * (float)vv[3];
      acc += p1.x * (float)vv[4] + p1.y * (float)vv[5] + p1.z * (float)vv[6] + p1.w * (float)vv[7];
    }
    opart[a * 9 + ch] = acc;
    __syncthreads();
    if (tid < 32) {
      float t = 0.f;
#pragma unroll
      for (int i = 0; i < 8; ++i) t += opart[tid * 9 + i];
      outc[(size_t)(b * C_ + c) * HA_ + h * A_ + tid] = t / bsum;
    }
  }
}

// ---------------------------------------------------------------------------
// Kernel 3: head projections, raw dual-dtype weights.
// 512 seq blocks: eh bit0, rc bits1-4, s bits5-6, b bits7-8 (complete 512).
// Each: 32 rows x 32 e-cols. + 16 const blocks.
// ---------------------------------------------------------------------------
__global__ __launch_bounds__(256) void hproj_kernel(
    const bf16* __restrict__ outs, const float* __restrict__ outc,
    const void* __restrict__ hws_raw, const void* __restrict__ hwc_raw,
    const unsigned int* __restrict__ x0, void* __restrict__ out)
{
  __shared__ __attribute__((aligned(16))) bf16 wt[32 * 264];   // 16896 B
  bool isf32 = detect_f32_fast(x0);
  int bid = blockIdx.x, tid = threadIdx.x;
  if (bid < 512) {
    int eh = bid & 1, rc = (bid >> 1) & 15, s = (bid >> 5) & 3, b = (bid >> 7) & 3;
    // stage W^T for this block's 32 e-columns: wt[e_loc][f], stride 264
    for (int idx = tid; idx < HA_ * 4; idx += 256) {   // 1024 chunks of 8 e
      int f = idx >> 2, ec = idx & 3;
      bf16x8 v = ld8(hws_raw, (size_t)s * HA_ * E_ + (size_t)f * E_ + eh * 32 + ec * 8, isf32);
#pragma unroll
      for (int j = 0; j < 8; ++j) wt[(ec * 8 + j) * 264 + f] = v[j];
    }
    __syncthreads();
    int lane = tid & 63, wave = tid >> 6, quad = lane >> 4, r = lane & 15;
    int rowh = wave & 1, ntw = wave >> 1;
    int row0 = rc * 32 + rowh * 16;
    const size_t xbase = (size_t)(b * S_ + s) * L_ * HA_;
    bf16x8 af[8];
#pragma unroll
    for (int kc = 0; kc < 8; ++kc)
      af[kc] = *(const bf16x8*)&outs[xbase + (size_t)(row0 + r) * HA_ + kc * 32 + quad * 8];
    f32x4 acc = {0.f,0.f,0.f,0.f};
#pragma unroll
    for (int kc = 0; kc < 8; ++kc) {
      bf16x8 bfr = *(const bf16x8*)&wt[(ntw * 16 + r) * 264 + kc * 32 + quad * 8];
      acc = __builtin_amdgcn_mfma_f32_16x16x32_bf16(af[kc], bfr, acc, 0,0,0);
    }
#pragma unroll
    for (int reg = 0; reg < 4; ++reg) {
      int row = row0 + quad * 4 + reg;
      int e = eh * 32 + ntw * 16 + r;
      size_t oidx = ((size_t)(b * S_ + s) * L_ + row) * E_ + e;
      if (isf32) ((float*)out)[oidx] = acc[reg];
      else       ((bf16*)out)[oidx]  = (bf16)acc[reg];
    }
  } else {
    float* opart = (float*)wt;       // reuse LDS: [4][68]
    int i2 = bid - 512;
    int b = i2 >> 2, c = i2 & 3;
    int fc = tid >> 6, e = tid & 63;
    const float* oc = outc + (size_t)(b * C_ + c) * HA_;
    float acc = 0.f;
#pragma unroll 4
    for (int fo = 0; fo < 64; ++fo) {
      int f = fc * 64 + fo;
      acc += oc[f] * ldf(hwc_raw, ((size_t)c * HA_ + f) * E_ + e, isf32);
    }
    opart[fc * 68 + e] = acc;
    __syncthreads();
    if (tid < 64) {
      float t = (opart[0 * 68 + tid] + opart[1 * 68 + tid]) +
                (opart[2 * 68 + tid] + opart[3 * 68 + tid]);
      size_t oidx = (size_t)B_ * S_ * L_ * E_ + (size_t)(b * C_ + c) * E_ + tid;
      if (isf32) ((float*)out)[oidx] = t;
      else       ((bf16*)out)[oidx]  = (bf16)t;
    }
  }
}

extern "C" void kernel_launch(void* const* d_in, const int* in_sizes, int n_in,
                              void* d_out, int out_size, void* d_ws, size_t ws_size,
                              hipStream_t stream) {
  char* ws = (char*)d_ws;
  bf16* qs    = (bf16*)(ws + OFF_QS);
  bf16* kall  = (bf16*)(ws + OFF_KALL);
  bf16* vt    = (bf16*)(ws + OFF_VT);
  bf16* outs  = (bf16*)(ws + OFF_OUTS);
  float* outc = (float*)(ws + OFF_OUTC);
  const int* maskp = (const int*)d_in[14];
  const unsigned int* x0 = (const unsigned int*)d_in[0];

  proj_kernel<<<1152, 256, 0, stream>>>(d_in[0], d_in[1], d_in[2], d_in[4], d_in[5],
                                        d_in[6], d_in[7], d_in[8], d_in[10], d_in[11],
                                        qs, kall, vt);
  attn_kernel<<<1152, 256, 0, stream>>>(qs, kall, vt, maskp, outs,
                                        d_in[3], d_in[9], x0, outc);
  hproj_kernel<<<528, 256, 0, stream>>>(outs, outc, d_in[12], d_in[13], x0, d_out);
}

// Round 12
// 160.906 us; speedup vs baseline: 1.0062x; 1.0062x over previous
//
#include <hip/hip_runtime.h>
#include <hip/hip_bf16.h>

#define B_ 4
#define S_ 4
#define C_ 4
#define L_ 512
#define E_ 64
#define A_ 32
#define H_ 8
#define HA_ 256      // H_*A_
#define KREAL 2052   // S_*L_ + C_
#define KP 2112      // padded to 33*64
#define NKT 33
#define SCALE 0.17677669529663687f   // 1/sqrt(32)
#define SCALE2 0.25503486321392056f  // log2(e)/sqrt(32)  (Q pre-scale, exp2 domain)
#define NEGINF (-__builtin_inff())

using bf16  = __bf16;
using bf16x8 = __attribute__((ext_vector_type(8))) __bf16;
using f32x4  = __attribute__((ext_vector_type(4))) float;

// workspace layout (byte offsets)
#define OFF_QS    0ull            // bf16 [B][S][H][L][A]  (pre-scaled by SCALE2)
#define OFF_KALL  4194304ull      // bf16 [B][H][KP][A]
#define OFF_VT    8519680ull      // bf16 [B][H][A][KP]
#define OFF_OUTS  12845056ull     // bf16 [B][S][L][HA]
#define OFF_OUTC  17039360ull     // f32  [B][C][HA]
// total ~17.1 MB

// ---------------------------------------------------------------------------
// Ballot-based dtype detection: no barriers, no atomics, wave-uniform.
// ---------------------------------------------------------------------------
__device__ __forceinline__ bool detect_f32_fast(const unsigned int* __restrict__ x0)
{
  unsigned v = x0[threadIdx.x & 63];
  int e = (int)((v >> 7) & 0xFF);
  bool weird = (e == 0xFF || e < 0x60 || e > 0x9F);
  unsigned long long m = __ballot(weird);
  return __builtin_popcountll(m) > 16;
}

// dual-dtype loads
__device__ __forceinline__ bf16x8 ld8(const void* p, size_t idx, bool isf32) {
  if (isf32) {
    const float* f = (const float*)p + idx;
    float4 lo = *(const float4*)f;
    float4 hi = *(const float4*)(f + 4);
    bf16x8 v;
    v[0] = (bf16)lo.x; v[1] = (bf16)lo.y; v[2] = (bf16)lo.z; v[3] = (bf16)lo.w;
    v[4] = (bf16)hi.x; v[5] = (bf16)hi.y; v[6] = (bf16)hi.z; v[7] = (bf16)hi.w;
    return v;
  }
  return *(const bf16x8*)((const bf16*)p + idx);
}
__device__ __forceinline__ float ldf(const void* p, size_t idx, bool isf32) {
  return isf32 ? ((const float*)p)[idx] : (float)((const bf16*)p)[idx];
}

// ---------------------------------------------------------------------------
// Kernel 1: QKV projections (MFMA), raw dual-dtype inputs.
// 1024 seq blocks (h bits0-2, lc8 bits3-5, s bits6-7, b bits8-9) + 128 const.
// ---------------------------------------------------------------------------
__global__ __launch_bounds__(256) void proj_kernel(
    const void* __restrict__ xq, const void* __restrict__ xk, const void* __restrict__ xv,
    const void* __restrict__ kc_in, const void* __restrict__ vc_in,
    const void* __restrict__ wq, const void* __restrict__ wk, const void* __restrict__ wv,
    const void* __restrict__ wkc, const void* __restrict__ wvc,
    bf16* __restrict__ qs, bf16* __restrict__ kall, bf16* __restrict__ vt)
{
  bool isf32 = detect_f32_fast((const unsigned int*)xq);
  int bid = blockIdx.x;
  int tid = threadIdx.x;
  if (bid < 1024) {
    int h = bid & 7, lc8 = (bid >> 3) & 7, s = (bid >> 6) & 3, b = (bid >> 8) & 3;
    __shared__ bf16 wt[3 * 32 * 72];      // W^T [a][e], stride 72
    __shared__ bf16 v_lds[32 * 72];       // V^T tile [a][l_local(64)], stride 72
    {
      size_t hb = (size_t)(s * H_ + h) * E_ * A_;
      int e = tid >> 2, ac = tid & 3;
      bf16x8 vq = ld8(wq, hb + e * 32 + ac * 8, isf32);
      bf16x8 vk = ld8(wk, hb + e * 32 + ac * 8, isf32);
      bf16x8 vv = ld8(wv, hb + e * 32 + ac * 8, isf32);
#pragma unroll
      for (int j = 0; j < 8; ++j) {
        int a = ac * 8 + j;
        wt[0 * 2304 + a * 72 + e] = vq[j];
        wt[1 * 2304 + a * 72 + e] = vk[j];
        wt[2 * 2304 + a * 72 + e] = vv[j];
      }
    }
    __syncthreads();
    int lane = tid & 63, wave = tid >> 6;
    int quad = lane >> 4, r = lane & 15;
    const size_t xbase = (size_t)(b * S_ + s) * L_ * E_;
    const size_t qsb   = (size_t)((b * S_ + s) * H_ + h) * L_ * A_;
    const size_t kab   = (size_t)(b * H_ + h) * KP * A_;
    const size_t vtb   = (size_t)(b * H_ + h) * A_ * KP;
    int lloc0 = wave * 16;
    int row0 = lc8 * 64 + lloc0;
    size_t rowoff = xbase + (size_t)(row0 + r) * E_ + quad * 8;
    bf16x8 aq0 = ld8(xq, rowoff, isf32);
    bf16x8 aq1 = ld8(xq, rowoff + 32, isf32);
    bf16x8 ak0 = ld8(xk, rowoff, isf32);
    bf16x8 ak1 = ld8(xk, rowoff + 32, isf32);
    bf16x8 av0 = ld8(xv, rowoff, isf32);
    bf16x8 av1 = ld8(xv, rowoff + 32, isf32);
#pragma unroll
    for (int nt = 0; nt < 2; ++nt) {
      bf16x8 bq0 = *(const bf16x8*)&wt[(nt * 16 + r) * 72 + 0 + quad * 8];
      bf16x8 bq1 = *(const bf16x8*)&wt[(nt * 16 + r) * 72 + 32 + quad * 8];
      bf16x8 bk0 = *(const bf16x8*)&wt[2304 + (nt * 16 + r) * 72 + 0 + quad * 8];
      bf16x8 bk1 = *(const bf16x8*)&wt[2304 + (nt * 16 + r) * 72 + 32 + quad * 8];
      bf16x8 bv0 = *(const bf16x8*)&wt[4608 + (nt * 16 + r) * 72 + 0 + quad * 8];
      bf16x8 bv1 = *(const bf16x8*)&wt[4608 + (nt * 16 + r) * 72 + 32 + quad * 8];
      f32x4 accq = {0.f,0.f,0.f,0.f}, acck = {0.f,0.f,0.f,0.f}, accv = {0.f,0.f,0.f,0.f};
      accq = __builtin_amdgcn_mfma_f32_16x16x32_bf16(aq0, bq0, accq, 0,0,0);
      accq = __builtin_amdgcn_mfma_f32_16x16x32_bf16(aq1, bq1, accq, 0,0,0);
      acck = __builtin_amdgcn_mfma_f32_16x16x32_bf16(ak0, bk0, acck, 0,0,0);
      acck = __builtin_amdgcn_mfma_f32_16x16x32_bf16(ak1, bk1, acck, 0,0,0);
      accv = __builtin_amdgcn_mfma_f32_16x16x32_bf16(av0, bv0, accv, 0,0,0);
      accv = __builtin_amdgcn_mfma_f32_16x16x32_bf16(av1, bv1, accv, 0,0,0);
#pragma unroll
      for (int reg = 0; reg < 4; ++reg) {
        int l = row0 + quad * 4 + reg;
        int a = nt * 16 + r;
        qs[qsb + (size_t)l * A_ + a]              = (bf16)(accq[reg] * SCALE2);
        kall[kab + (size_t)(s * L_ + l) * A_ + a] = (bf16)acck[reg];
        v_lds[a * 72 + lloc0 + quad * 4 + reg]    = (bf16)accv[reg];
      }
    }
    __syncthreads();
    {
      int a = tid >> 3, c8 = tid & 7;
      *(bf16x8*)&vt[vtb + (size_t)a * KP + s * L_ + lc8 * 64 + c8 * 8] =
          *(const bf16x8*)&v_lds[a * 72 + c8 * 8];
    }
  } else {
    int cid = bid - 1024;
    int b = cid >> 5, c = (cid >> 3) & 3, h = cid & 7;
    if (tid < 32) {
      int a = tid;
      float kacc = 0.f, vacc = 0.f;
#pragma unroll 8
      for (int e = 0; e < E_; ++e) {
        float xke = ldf(kc_in, (b * C_ + c) * E_ + e, isf32);
        float xve = ldf(vc_in, (b * C_ + c) * E_ + e, isf32);
        float wke = ldf(wkc, ((size_t)(c * H_ + h) * E_ + e) * A_ + a, isf32);
        float wve = ldf(wvc, ((size_t)(c * H_ + h) * E_ + e) * A_ + a, isf32);
        kacc += xke * wke;
        vacc += xve * wve;
      }
      kall[((size_t)(b * H_ + h) * KP + (S_ * L_ + c)) * A_ + a] = (bf16)kacc;
      vt[((size_t)(b * H_ + h) * A_ + a) * KP + (S_ * L_ + c)]   = (bf16)vacc;
    }
    if (c == 0) {  // zero pad keys 2052..2111
      for (int idx = tid; idx < 60 * 32; idx += 256) {
        int k = KREAL + (idx >> 5), a = idx & 31;
        kall[((size_t)(b * H_ + h) * KP + k) * A_ + a] = (bf16)0.f;
        vt[((size_t)(b * H_ + h) * A_ + a) * KP + k]   = (bf16)0.f;
      }
    }
  }
}

// ---------------------------------------------------------------------------
// Kernel 2: flash attention, 2-tile (128-key) staging per barrier round.
// blocks 0..1023: R7/R9 balanced qt swizzle; active-tile list via incremental
// counters (named regs only). blocks 1024..1151: constant-query attention.
// ---------------------------------------------------------------------------
__global__ __launch_bounds__(256) void attn_kernel(
    const bf16* __restrict__ qs, const bf16* __restrict__ kall, const bf16* __restrict__ vt,
    const int* __restrict__ maskp, bf16* __restrict__ outs,
    const void* __restrict__ qc_raw, const void* __restrict__ wqc_raw,
    const unsigned int* __restrict__ x0, float* __restrict__ outc)
{
  __shared__ __attribute__((aligned(16))) bf16 kt_lds[128 * 40];    // 10240 B (2 tiles)
  __shared__ __attribute__((aligned(16))) bf16 vt_lds[32 * 136];    // 8704 B (128 keys)
  __shared__ __attribute__((aligned(16))) bf16 p_lds[4 * 16 * 72];  // 9216 B
  int bid = blockIdx.x, tid = threadIdx.x;
  int lane = tid & 63, wave = tid >> 6, quad = lane >> 4, r = lane & 15;
  if (bid < 1024) {
    int h = bid & 7;
    int q0 = (bid >> 3) & 7;
    int s = (bid >> 6) & 3;
    int b = (bid >> 8) & 3;
    int base = (q0 + 2 * (b >> 1)) & 7;
    int qt = (b & 1) ? 7 - base : base;
    bool causal = (*maskp != 0);
    int wrow = qt * 64 + wave * 16;
    int lrow = wrow + r;

    const size_t qsb = (size_t)((b * S_ + s) * H_ + h) * L_ * A_;
    bf16x8 aq = *(const bf16x8*)&qs[qsb + (size_t)(wrow + r) * A_ + quad * 8];

    f32x4 o[2];
    { f32x4 z = {0.f,0.f,0.f,0.f}; o[0] = z; o[1] = z; }
    float l_run = 0.f;

    const size_t kbase = (size_t)(b * H_ + h) * KP * A_;
    const size_t vbase = (size_t)(b * H_ + h) * A_ * KP;
    const int pbase = wave * 16 * 72;
    int rowg = tid >> 2, c4 = tid & 3;   // K staging: 64 row-groups x 4 chunks
    int a8 = tid >> 3, c8 = tid & 7;     // V staging: 32 a x 8 chunks

    // compute one 64-key tile resident in LDS half `half`
    auto compute_tile = [&](int kt, int half) {
      int kmod = (kt & 7) * 64;
      if (causal && kt < 32 && kmod >= wrow + 16) return;   // wave-level skip
      bool fullv = (kt < 32) && (!causal || kmod + 63 <= wrow);
      f32x4 sf[4];
#pragma unroll
      for (int kg = 0; kg < 4; ++kg) {
        bf16x8 ka = *(const bf16x8*)&kt_lds[(half * 64 + kg * 16 + r) * 40 + quad * 8];
        f32x4 z = {0.f,0.f,0.f,0.f};
        sf[kg] = __builtin_amdgcn_mfma_f32_16x16x32_bf16(ka, aq, z, 0,0,0);
      }
      if (!fullv) {
        int thresh = (kt < 32) ? (lrow - kmod) : 3;
#pragma unroll
        for (int kg = 0; kg < 4; ++kg)
#pragma unroll
          for (int reg = 0; reg < 4; ++reg)
            if (kg * 16 + quad * 4 + reg > thresh) sf[kg][reg] = NEGINF;
      }
      // scale-free softmax: p = 2^s2 (uniform scale cancels in o/l)
      float psum = 0.f;
#pragma unroll
      for (int kg = 0; kg < 4; ++kg) {
        float p0 = exp2f(sf[kg][0]);
        float p1 = exp2f(sf[kg][1]);
        float p2 = exp2f(sf[kg][2]);
        float p3 = exp2f(sf[kg][3]);
        psum += (p0 + p1) + (p2 + p3);
        union { bf16 hh[4]; uint2 u2; } pk;
        pk.hh[0] = (bf16)p0; pk.hh[1] = (bf16)p1; pk.hh[2] = (bf16)p2; pk.hh[3] = (bf16)p3;
        *(uint2*)&p_lds[pbase + r * 72 + kg * 16 + quad * 4] = pk.u2;
      }
      psum += __shfl_xor(psum, 16);
      psum += __shfl_xor(psum, 32);
      l_run += psum;
#pragma unroll
      for (int kc2 = 0; kc2 < 2; ++kc2) {
        bf16x8 ap = *(const bf16x8*)&p_lds[pbase + r * 72 + kc2 * 32 + quad * 8];
#pragma unroll
        for (int nt = 0; nt < 2; ++nt) {
          bf16x8 bv = *(const bf16x8*)&vt_lds[(nt * 16 + r) * 136 + half * 64 + kc2 * 32 + quad * 8];
          o[nt] = __builtin_amdgcn_mfma_f32_16x16x32_bf16(ap, bv, o[nt], 0,0,0);
        }
      }
    };

    // active-tile list: groups g=0..3 carry tiles g*8+m (m<=qtc), then tile 32
    int qtc = causal ? qt : 7;
    int nact = 4 * (qtc + 1) + 1;
    int g = 0, mn = 0, ktcur = 0;
#pragma unroll 1
    for (int i = 0; i < nact; i += 2) {
      int ktA = ktcur;
      bool haveB = (i + 1 < nact);
      int ktB = ktA;
      if (haveB) {
        mn++; if (mn > qtc) { mn = 0; g++; }
        ktB = (g >= 4) ? 32 : g * 8 + mn;
      }
      if (i + 2 < nact) {
        mn++; if (mn > qtc) { mn = 0; g++; }
        ktcur = (g >= 4) ? 32 : g * 8 + mn;
      }
      bf16x8 kAr = *(const bf16x8*)&kall[kbase + (size_t)(ktA * 64 + rowg) * A_ + c4 * 8];
      bf16x8 kBr = *(const bf16x8*)&kall[kbase + (size_t)(ktB * 64 + rowg) * A_ + c4 * 8];
      bf16x8 vAr = *(const bf16x8*)&vt[vbase + (size_t)a8 * KP + ktA * 64 + c8 * 8];
      bf16x8 vBr = *(const bf16x8*)&vt[vbase + (size_t)a8 * KP + ktB * 64 + c8 * 8];
      __syncthreads();   // previous round's LDS reads complete
      *(bf16x8*)&kt_lds[rowg * 40 + c4 * 8]        = kAr;
      *(bf16x8*)&kt_lds[(64 + rowg) * 40 + c4 * 8] = kBr;
      *(bf16x8*)&vt_lds[a8 * 136 + c8 * 8]         = vAr;
      *(bf16x8*)&vt_lds[a8 * 136 + 64 + c8 * 8]    = vBr;
      __syncthreads();   // both tiles staged
      compute_tile(ktA, 0);
      if (haveB) compute_tile(ktB, 1);
    }
    const size_t obase = (size_t)(b * S_ + s) * L_ * HA_;
#pragma unroll
    for (int reg = 0; reg < 4; ++reg) {
      float lo = __shfl(l_run, (lane & 48) | (quad * 4 + reg));
      int orow = wrow + quad * 4 + reg;
#pragma unroll
      for (int nt = 0; nt < 2; ++nt) {
        int f = h * A_ + nt * 16 + r;
        outs[obase + (size_t)orow * HA_ + f] = (bf16)(o[nt][reg] / lo);
      }
    }
  } else {
    // ---- constant-query attention: blocks 1024..1151 = (b,c,h), raw inputs --
    bool isf32 = detect_f32_fast(x0);
    float* parr  = (float*)kt_lds;             // 8448 B <= 10240 ok
    float* qsh   = (float*)vt_lds;             // [32]
    float* red   = (float*)vt_lds + 64;        // [8]
    float* opart = (float*)vt_lds + 128;       // [32*9] -> 1312 B <= 8704 ok
    int cid = bid - 1024;
    int b = cid >> 5, c = (cid >> 3) & 3, h = cid & 7;
    if (tid < 32) {
      float acc = 0.f;
#pragma unroll 8
      for (int e = 0; e < E_; ++e)
        acc += ldf(qc_raw, (b * C_ + c) * E_ + e, isf32) *
               ldf(wqc_raw, ((size_t)(c * H_ + h) * E_ + e) * A_ + tid, isf32);
      qsh[tid] = acc * SCALE;
    }
    if (tid >= 192 && tid < 192 + (KP - KREAL)) parr[KREAL + tid - 192] = 0.f;
    __syncthreads();
    const size_t kbase = (size_t)(b * H_ + h) * KP * A_;
    float lmax = -1e30f;
#pragma unroll 1
    for (int j = 0; j < 9; ++j) {
      int k = tid + j * 256;
      if (k < KREAL) {
        bf16x8 k0 = *(const bf16x8*)&kall[kbase + (size_t)k * A_ + 0];
        bf16x8 k1 = *(const bf16x8*)&kall[kbase + (size_t)k * A_ + 8];
        bf16x8 k2 = *(const bf16x8*)&kall[kbase + (size_t)k * A_ + 16];
        bf16x8 k3 = *(const bf16x8*)&kall[kbase + (size_t)k * A_ + 24];
        float d = 0.f;
#pragma unroll
        for (int i = 0; i < 8; ++i) {
          d += qsh[i]      * (float)k0[i];
          d += qsh[8 + i]  * (float)k1[i];
          d += qsh[16 + i] * (float)k2[i];
          d += qsh[24 + i] * (float)k3[i];
        }
        parr[k] = d;
        lmax = fmaxf(lmax, d);
      }
    }
#pragma unroll
    for (int dlt = 1; dlt < 64; dlt <<= 1) lmax = fmaxf(lmax, __shfl_xor(lmax, dlt));
    if (lane == 0) red[wave] = lmax;
    __syncthreads();
    float bmax = fmaxf(fmaxf(red[0], red[1]), fmaxf(red[2], red[3]));
    float lsum = 0.f;
#pragma unroll 1
    for (int j = 0; j < 9; ++j) {
      int k = tid + j * 256;
      if (k < KREAL) {
        float p = __expf(parr[k] - bmax);
        parr[k] = p;
        lsum += p;
      }
    }
#pragma unroll
    for (int dlt = 1; dlt < 64; dlt <<= 1) lsum += __shfl_xor(lsum, dlt);
    if (lane == 0) red[4 + wave] = lsum;
    __syncthreads();
    float bsum = (red[4] + red[5]) + (red[6] + red[7]);
    int a = tid >> 3, ch = tid & 7;
    const size_t vbase = (size_t)(b * H_ + h) * A_ * KP + (size_t)a * KP;
    float acc = 0.f;
#pragma unroll 1
    for (int j = 0; j < 33; ++j) {
      int kb = ch * 8 + j * 64;
      bf16x8 vv = *(const bf16x8*)&vt[vbase + kb];
      float4 p0 = *(float4*)&parr[kb];
      float4 p1 = *(float4*)&parr[kb + 4];
      acc += p0.x * (float)vv[0] + p0.y * (float)vv[1] + p0.z * (float)vv[2] + p0.w * (float)vv[3];
      acc += p1.x * (float)vv[4] + p1.y * (float)vv[5] + p1.z * (float)vv[6] + p1.w * (float)vv[7];
    }
    opart[a * 9 + ch] = acc;
    __syncthreads();
    if (tid < 32) {
      float t = 0.f;
#pragma unroll
      for (int i = 0; i < 8; ++i) t += opart[tid * 9 + i];
      outc[(size_t)(b * C_ + c) * HA_ + h * A_ + tid] = t / bsum;
    }
  }
}

// ---------------------------------------------------------------------------
// Kernel 3: head projections, raw dual-dtype weights.
// 512 seq blocks: eh bit0, rc bits1-4, s bits5-6, b bits7-8. + 16 const.
// ---------------------------------------------------------------------------
__global__ __launch_bounds__(256) void hproj_kernel(
    const bf16* __restrict__ outs, const float* __restrict__ outc,
    const void* __restrict__ hws_raw, const void* __restrict__ hwc_raw,
    const unsigned int* __restrict__ x0, void* __restrict__ out)
{
  __shared__ __attribute__((aligned(16))) bf16 wt[32 * 264];   // 16896 B
  bool isf32 = detect_f32_fast(x0);
  int bid = blockIdx.x, tid = threadIdx.x;
  if (bid < 512) {
    int eh = bid & 1, rc = (bid >> 1) & 15, s = (bid >> 5) & 3, b = (bid >> 7) & 3;
    for (int idx = tid; idx < HA_ * 4; idx += 256) {
      int f = idx >> 2, ec = idx & 3;
      bf16x8 v = ld8(hws_raw, (size_t)s * HA_ * E_ + (size_t)f * E_ + eh * 32 + ec * 8, isf32);
#pragma unroll
      for (int j = 0; j < 8; ++j) wt[(ec * 8 + j) * 264 + f] = v[j];
    }
    __syncthreads();
    int lane = tid & 63, wave = tid >> 6, quad = lane >> 4, r = lane & 15;
    int rowh = wave & 1, ntw = wave >> 1;
    int row0 = rc * 32 + rowh * 16;
    const size_t xbase = (size_t)(b * S_ + s) * L_ * HA_;
    bf16x8 af[8];
#pragma unroll
    for (int kc = 0; kc < 8; ++kc)
      af[kc] = *(const bf16x8*)&outs[xbase + (size_t)(row0 + r) * HA_ + kc * 32 + quad * 8];
    f32x4 acc = {0.f,0.f,0.f,0.f};
#pragma unroll
    for (int kc = 0; kc < 8; ++kc) {
      bf16x8 bfr = *(const bf16x8*)&wt[(ntw * 16 + r) * 264 + kc * 32 + quad * 8];
      acc = __builtin_amdgcn_mfma_f32_16x16x32_bf16(af[kc], bfr, acc, 0,0,0);
    }
#pragma unroll
    for (int reg = 0; reg < 4; ++reg) {
      int row = row0 + quad * 4 + reg;
      int e = eh * 32 + ntw * 16 + r;
      size_t oidx = ((size_t)(b * S_ + s) * L_ + row) * E_ + e;
      if (isf32) ((float*)out)[oidx] = acc[reg];
      else       ((bf16*)out)[oidx]  = (bf16)acc[reg];
    }
  } else {
    float* opart = (float*)wt;       // reuse LDS: [4][68]
    int i2 = bid - 512;
    int b = i2 >> 2, c = i2 & 3;
    int fc = tid >> 6, e = tid & 63;
    const float* oc = outc + (size_t)(b * C_ + c) * HA_;
    float acc = 0.f;
#pragma unroll 4
    for (int fo = 0; fo < 64; ++fo) {
      int f = fc * 64 + fo;
      acc += oc[f] * ldf(hwc_raw, ((size_t)c * HA_ + f) * E_ + e, isf32);
    }
    opart[fc * 68 + e] = acc;
    __syncthreads();
    if (tid < 64) {
      float t = (opart[0 * 68 + tid] + opart[1 * 68 + tid]) +
                (opart[2 * 68 + tid] + opart[3 * 68 + tid]);
      size_t oidx = (size_t)B_ * S_ * L_ * E_ + (size_t)(b * C_ + c) * E_ + tid;
      if (isf32) ((float*)out)[oidx] = t;
      else       ((bf16*)out)[oidx]  = (bf16)t;
    }
  }
}

extern "C" void kernel_launch(void* const* d_in, const int* in_sizes, int n_in,
                              void* d_out, int out_size, void* d_ws, size_t ws_size,
                              hipStream_t stream) {
  char* ws = (char*)d_ws;
  bf16* qs    = (bf16*)(ws + OFF_QS);
  bf16* kall  = (bf16*)(ws + OFF_KALL);
  bf16* vt    = (bf16*)(ws + OFF_VT);
  bf16* outs  = (bf16*)(ws + OFF_OUTS);
  float* outc = (float*)(ws + OFF_OUTC);
  const int* maskp = (const int*)d_in[14];
  const unsigned int* x0 = (const unsigned int*)d_in[0];

  proj_kernel<<<1152, 256, 0, stream>>>(d_in[0], d_in[1], d_in[2], d_in[4], d_in[5],
                                        d_in[6], d_in[7], d_in[8], d_in[10], d_in[11],
                                        qs, kall, vt);
  attn_kernel<<<1152, 256, 0, stream>>>(qs, kall, vt, maskp, outs,
                                        d_in[3], d_in[9], x0, outc);
  hproj_kernel<<<528, 256, 0, stream>>>(outs, outc, d_in[12], d_in[13], x0, d_out);
}

// Round 14
// 159.152 us; speedup vs baseline: 1.0173x; 1.0110x over previous
//
#include <hip/hip_runtime.h>
#include <hip/hip_bf16.h>

#define B_ 4
#define S_ 4
#define C_ 4
#define L_ 512
#define E_ 64
#define A_ 32
#define H_ 8
#define HA_ 256      // H_*A_
#define KREAL 2052   // S_*L_ + C_
#define KP 2112      // padded to 33*64
#define NKT 33
#define SCALE 0.17677669529663687f   // 1/sqrt(32)
#define SCALE2 0.25503486321392056f  // log2(e)/sqrt(32)  (Q pre-scale, exp2 domain)
#define NEGINF (-__builtin_inff())

using bf16  = __bf16;
using bf16x8 = __attribute__((ext_vector_type(8))) __bf16;
using f32x4  = __attribute__((ext_vector_type(4))) float;

// workspace layout (byte offsets)
#define OFF_QS    0ull            // bf16 [B][S][H][L][A]  (pre-scaled by SCALE2)
#define OFF_KALL  4194304ull      // bf16 [B][H][KP][A]
#define OFF_VT    8519680ull      // bf16 [B][H][A][KP]
#define OFF_OUTS  12845056ull     // bf16 [B][S][L][HA]
#define OFF_OUTC  17039360ull     // f32  [B][C][HA]
// total ~17.1 MB

// ---------------------------------------------------------------------------
// Inline dtype detection (wave-uniform result).
// ---------------------------------------------------------------------------
__device__ __forceinline__ bool detect_f32(const unsigned int* __restrict__ x0,
                                           int* sh_cnt)
{
  if (threadIdx.x == 0) *sh_cnt = 0;
  __syncthreads();
  int weird = 0;
  for (int i = threadIdx.x; i < 1024; i += blockDim.x) {
    unsigned h = x0[i] & 0xffffu;
    int e = (int)((h >> 7) & 0xFF);
    if (e == 0xFF || e < 0x60 || e > 0x9F) weird++;
  }
  atomicAdd(sh_cnt, weird);
  __syncthreads();
  int cnt = *sh_cnt;
  return __builtin_amdgcn_readfirstlane(cnt) > 256;
}

// dual-dtype loads
__device__ __forceinline__ bf16x8 ld8(const void* p, size_t idx, bool isf32) {
  if (isf32) {
    const float* f = (const float*)p + idx;
    float4 lo = *(const float4*)f;
    float4 hi = *(const float4*)(f + 4);
    bf16x8 v;
    v[0] = (bf16)lo.x; v[1] = (bf16)lo.y; v[2] = (bf16)lo.z; v[3] = (bf16)lo.w;
    v[4] = (bf16)hi.x; v[5] = (bf16)hi.y; v[6] = (bf16)hi.z; v[7] = (bf16)hi.w;
    return v;
  }
  return *(const bf16x8*)((const bf16*)p + idx);
}
__device__ __forceinline__ float ldf(const void* p, size_t idx, bool isf32) {
  return isf32 ? ((const float*)p)[idx] : (float)((const bf16*)p)[idx];
}

// ---------------------------------------------------------------------------
// Kernel 1: QKV projections (MFMA), reading RAW inputs (dual-dtype).
// qs pre-scaled by SCALE2. blocks 0..255 seq; 256..383 const rows + pads.
// ---------------------------------------------------------------------------
__global__ __launch_bounds__(256) void proj_kernel(
    const void* __restrict__ xq, const void* __restrict__ xk, const void* __restrict__ xv,
    const void* __restrict__ kc_in, const void* __restrict__ vc_in,
    const void* __restrict__ wq, const void* __restrict__ wk, const void* __restrict__ wv,
    const void* __restrict__ wkc, const void* __restrict__ wvc,
    bf16* __restrict__ qs, bf16* __restrict__ kall, bf16* __restrict__ vt)
{
  __shared__ int sh_cnt;
  bool isf32 = detect_f32((const unsigned int*)xq, &sh_cnt);
  int bid = blockIdx.x;
  int tid = threadIdx.x;
  if (bid < 256) {
    int b = bid >> 6, s = (bid >> 4) & 3, h = (bid >> 1) & 7, lc = bid & 1;
    __shared__ bf16 wt[3 * 32 * 72];      // W^T [a][e], stride 72
    __shared__ bf16 v_lds[32 * 264];      // V^T tile [a][l_local], stride 264
    {
      size_t hb = (size_t)(s * H_ + h) * E_ * A_;
      int e = tid >> 2, ac = tid & 3;
      bf16x8 vq = ld8(wq, hb + e * 32 + ac * 8, isf32);
      bf16x8 vk = ld8(wk, hb + e * 32 + ac * 8, isf32);
      bf16x8 vv = ld8(wv, hb + e * 32 + ac * 8, isf32);
#pragma unroll
      for (int j = 0; j < 8; ++j) {
        int a = ac * 8 + j;
        wt[0 * 2304 + a * 72 + e] = vq[j];
        wt[1 * 2304 + a * 72 + e] = vk[j];
        wt[2 * 2304 + a * 72 + e] = vv[j];
      }
    }
    __syncthreads();
    int lane = tid & 63, wave = tid >> 6;
    int quad = lane >> 4, r = lane & 15;
    bf16x8 bq[2][2], bk[2][2], bv[2][2];
#pragma unroll
    for (int kc = 0; kc < 2; ++kc)
#pragma unroll
      for (int nt = 0; nt < 2; ++nt) {
        int off = (nt * 16 + r) * 72 + kc * 32 + quad * 8;
        bq[kc][nt] = *(const bf16x8*)&wt[off];
        bk[kc][nt] = *(const bf16x8*)&wt[2304 + off];
        bv[kc][nt] = *(const bf16x8*)&wt[4608 + off];
      }
    const size_t xbase = (size_t)(b * S_ + s) * L_ * E_;
    const size_t qsb   = (size_t)((b * S_ + s) * H_ + h) * L_ * A_;
    const size_t kab   = (size_t)(b * H_ + h) * KP * A_;
    const size_t vtb   = (size_t)(b * H_ + h) * A_ * KP;
#pragma unroll 1
    for (int i = 0; i < 4; ++i) {
      int lloc0 = (wave * 4 + i) * 16;
      int row0 = lc * 256 + lloc0;
      size_t rowoff = xbase + (size_t)(row0 + r) * E_ + quad * 8;
      bf16x8 aq0 = ld8(xq, rowoff, isf32);
      bf16x8 aq1 = ld8(xq, rowoff + 32, isf32);
      bf16x8 ak0 = ld8(xk, rowoff, isf32);
      bf16x8 ak1 = ld8(xk, rowoff + 32, isf32);
      bf16x8 av0 = ld8(xv, rowoff, isf32);
      bf16x8 av1 = ld8(xv, rowoff + 32, isf32);
#pragma unroll
      for (int nt = 0; nt < 2; ++nt) {
        f32x4 accq = {0.f,0.f,0.f,0.f}, acck = {0.f,0.f,0.f,0.f}, accv = {0.f,0.f,0.f,0.f};
        accq = __builtin_amdgcn_mfma_f32_16x16x32_bf16(aq0, bq[0][nt], accq, 0,0,0);
        accq = __builtin_amdgcn_mfma_f32_16x16x32_bf16(aq1, bq[1][nt], accq, 0,0,0);
        acck = __builtin_amdgcn_mfma_f32_16x16x32_bf16(ak0, bk[0][nt], acck, 0,0,0);
        acck = __builtin_amdgcn_mfma_f32_16x16x32_bf16(ak1, bk[1][nt], acck, 0,0,0);
        accv = __builtin_amdgcn_mfma_f32_16x16x32_bf16(av0, bv[0][nt], accv, 0,0,0);
        accv = __builtin_amdgcn_mfma_f32_16x16x32_bf16(av1, bv[1][nt], accv, 0,0,0);
#pragma unroll
        for (int reg = 0; reg < 4; ++reg) {
          int l = row0 + quad * 4 + reg;
          int a = nt * 16 + r;
          qs[qsb + (size_t)l * A_ + a]              = (bf16)(accq[reg] * SCALE2);
          kall[kab + (size_t)(s * L_ + l) * A_ + a] = (bf16)acck[reg];
          v_lds[a * 264 + lloc0 + quad * 4 + reg]   = (bf16)accv[reg];
        }
      }
    }
    __syncthreads();
    {
      int a = tid >> 3, c8 = tid & 7;
      size_t rb = vtb + (size_t)a * KP + s * L_ + lc * 256;
#pragma unroll
      for (int j = 0; j < 4; ++j) {
        int chunk = j * 8 + c8;
        *(bf16x8*)&vt[rb + chunk * 8] = *(const bf16x8*)&v_lds[a * 264 + chunk * 8];
      }
    }
  } else {
    int cid = bid - 256;
    int b = cid >> 5, c = (cid >> 3) & 3, h = cid & 7;
    if (tid < 32) {
      int a = tid;
      float kacc = 0.f, vacc = 0.f;
#pragma unroll 8
      for (int e = 0; e < E_; ++e) {
        float xke = ldf(kc_in, (b * C_ + c) * E_ + e, isf32);
        float xve = ldf(vc_in, (b * C_ + c) * E_ + e, isf32);
        float wke = ldf(wkc, ((size_t)(c * H_ + h) * E_ + e) * A_ + a, isf32);
        float wve = ldf(wvc, ((size_t)(c * H_ + h) * E_ + e) * A_ + a, isf32);
        kacc += xke * wke;
        vacc += xve * wve;
      }
      kall[((size_t)(b * H_ + h) * KP + (S_ * L_ + c)) * A_ + a] = (bf16)kacc;
      vt[((size_t)(b * H_ + h) * A_ + a) * KP + (S_ * L_ + c)]   = (bf16)vacc;
    }
    if (c == 0) {  // zero pad keys 2052..2111
      for (int idx = tid; idx < 60 * 32; idx += 256) {
        int k = KREAL + (idx >> 5), a = idx & 31;
        kall[((size_t)(b * H_ + h) * KP + k) * A_ + a] = (bf16)0.f;
        vt[((size_t)(b * H_ + h) * A_ + a) * KP + k]   = (bf16)0.f;
      }
    }
  }
}

// ---------------------------------------------------------------------------
// Kernel 2: flash attention (blocks 0..1023, 64-row q-tiles, balanced qt
// swizzle — R7/R9 validated geometry) + constant-query attention
// (blocks 1024..1151, raw dual-dtype inputs).
//
// Placement model (validated R7): XCD = bid%8, CU = (bid>>3)%32; a CU's
// resident blocks are {c, c+256, c+512, c+768}. h=bid&7 keeps one head's
// K/V per XCD L2 (FETCH 24->6.4MB). qt from {q, 7-q, q+2, 7-(q+2)} gives
// every CU exactly 76 active tiles (was 20..132).
// Softmax is scale-free: p = 2^s2, no max subtraction (o/l cancels any
// uniform factor; |s2| <= ~11 so p <= 2^11; validated R8/R9).
// ---------------------------------------------------------------------------
__global__ __launch_bounds__(256) void attn_kernel(
    const bf16* __restrict__ qs, const bf16* __restrict__ kall, const bf16* __restrict__ vt,
    const int* __restrict__ maskp, bf16* __restrict__ outs,
    const void* __restrict__ qc_raw, const void* __restrict__ wqc_raw,
    const unsigned int* __restrict__ x0, float* __restrict__ outc)
{
  __shared__ __attribute__((aligned(16))) bf16 kt_lds[64 * 40];     // 5120 B
  __shared__ __attribute__((aligned(16))) bf16 vt_lds[32 * 72];     // 4608 B
  __shared__ __attribute__((aligned(16))) bf16 p_lds[4 * 16 * 72];  // 9216 B
  __shared__ int sh_cnt;
  int bid = blockIdx.x, tid = threadIdx.x;
  int lane = tid & 63, wave = tid >> 6, quad = lane >> 4, r = lane & 15;
  if (bid < 1024) {
    int h = bid & 7;
    int q0 = (bid >> 3) & 7;
    int s = (bid >> 6) & 3;
    int b = (bid >> 8) & 3;
    int base = (q0 + 2 * (b >> 1)) & 7;
    int qt = (b & 1) ? 7 - base : base;
    bool causal = (*maskp != 0);
    int wrow = qt * 64 + wave * 16;
    int lrow = wrow + r;
    int blockmax = qt * 64 + 63;

    const size_t qsb = (size_t)((b * S_ + s) * H_ + h) * L_ * A_;
    bf16x8 aq = *(const bf16x8*)&qs[qsb + (size_t)(wrow + r) * A_ + quad * 8];

    f32x4 o[2];
    { f32x4 z = {0.f,0.f,0.f,0.f}; o[0] = z; o[1] = z; }
    float l_run = 0.f;

    const size_t kbase = (size_t)(b * H_ + h) * KP * A_;
    const size_t vbase = (size_t)(b * H_ + h) * A_ * KP;
    const int pbase = wave * 16 * 72;

#pragma unroll 1
    for (int kt = 0; kt < NKT; ++kt) {
      int kmod = (kt & 7) * 64;
      if (causal && kt < 32 && kmod > blockmax) continue;   // block-level skip
      __syncthreads();
      {
        int krow = tid >> 2, c4 = tid & 3;
        *(bf16x8*)&kt_lds[krow * 40 + c4 * 8] =
            *(const bf16x8*)&kall[kbase + (size_t)(kt * 64 + krow) * A_ + c4 * 8];
        int a8 = tid >> 3, c8 = tid & 7;
        *(bf16x8*)&vt_lds[a8 * 72 + c8 * 8] =
            *(const bf16x8*)&vt[vbase + (size_t)a8 * KP + kt * 64 + c8 * 8];
      }
      __syncthreads();
      if (causal && kt < 32 && kmod >= wrow + 16) continue; // wave-level skip
      bool fullv = (kt < 32) && (!causal || kmod + 63 <= wrow);

      f32x4 sf[4];
#pragma unroll
      for (int kg = 0; kg < 4; ++kg) {
        bf16x8 ka = *(const bf16x8*)&kt_lds[(kg * 16 + r) * 40 + quad * 8];
        f32x4 z = {0.f,0.f,0.f,0.f};
        sf[kg] = __builtin_amdgcn_mfma_f32_16x16x32_bf16(ka, aq, z, 0,0,0);
      }
      if (!fullv) {
        int thresh = (kt < 32) ? (lrow - kmod) : 3;
#pragma unroll
        for (int kg = 0; kg < 4; ++kg)
#pragma unroll
          for (int reg = 0; reg < 4; ++reg)
            if (kg * 16 + quad * 4 + reg > thresh) sf[kg][reg] = NEGINF;
      }
      // scale-free softmax: p = 2^s2 (uniform scale cancels in o/l)
      float psum = 0.f;
#pragma unroll
      for (int kg = 0; kg < 4; ++kg) {
        float p0 = exp2f(sf[kg][0]);
        float p1 = exp2f(sf[kg][1]);
        float p2 = exp2f(sf[kg][2]);
        float p3 = exp2f(sf[kg][3]);
        psum += (p0 + p1) + (p2 + p3);
        union { bf16 hh[4]; uint2 u2; } pk;
        pk.hh[0] = (bf16)p0; pk.hh[1] = (bf16)p1; pk.hh[2] = (bf16)p2; pk.hh[3] = (bf16)p3;
        *(uint2*)&p_lds[pbase + r * 72 + kg * 16 + quad * 4] = pk.u2;
      }
      psum += __shfl_xor(psum, 16);
      psum += __shfl_xor(psum, 32);
      l_run += psum;
#pragma unroll
      for (int kc2 = 0; kc2 < 2; ++kc2) {
        bf16x8 ap = *(const bf16x8*)&p_lds[pbase + r * 72 + kc2 * 32 + quad * 8];
#pragma unroll
        for (int nt = 0; nt < 2; ++nt) {
          bf16x8 bv = *(const bf16x8*)&vt_lds[(nt * 16 + r) * 72 + kc2 * 32 + quad * 8];
          o[nt] = __builtin_amdgcn_mfma_f32_16x16x32_bf16(ap, bv, o[nt], 0,0,0);
        }
      }
    }
    const size_t obase = (size_t)(b * S_ + s) * L_ * HA_;
#pragma unroll
    for (int reg = 0; reg < 4; ++reg) {
      float lo = __shfl(l_run, (lane & 48) | (quad * 4 + reg));
      int orow = wrow + quad * 4 + reg;
#pragma unroll
      for (int nt = 0; nt < 2; ++nt) {
        int f = h * A_ + nt * 16 + r;
        outs[obase + (size_t)orow * HA_ + f] = (bf16)(o[nt][reg] / lo);
      }
    }
  } else {
    // ---- constant-query attention: blocks 1024..1151 = (b,c,h), raw inputs --
    bool isf32 = detect_f32(x0, &sh_cnt);
    float* parr  = (float*)p_lds;              // 8448 B <= 9216 ok
    float* qsh   = (float*)kt_lds;             // [32]
    float* red   = (float*)kt_lds + 64;        // [8]
    float* opart = (float*)kt_lds + 128;       // [32*9] <= 5120 B ok
    int cid = bid - 1024;
    int b = cid >> 5, c = (cid >> 3) & 3, h = cid & 7;
    if (tid < 32) {
      float acc = 0.f;
#pragma unroll 8
      for (int e = 0; e < E_; ++e)
        acc += ldf(qc_raw, (b * C_ + c) * E_ + e, isf32) *
               ldf(wqc_raw, ((size_t)(c * H_ + h) * E_ + e) * A_ + tid, isf32);
      qsh[tid] = acc * SCALE;
    }
    if (tid >= 192 && tid < 192 + (KP - KREAL)) parr[KREAL + tid - 192] = 0.f;
    __syncthreads();
    const size_t kbase = (size_t)(b * H_ + h) * KP * A_;
    float lmax = -1e30f;
#pragma unroll 1
    for (int j = 0; j < 9; ++j) {
      int k = tid + j * 256;
      if (k < KREAL) {
        bf16x8 k0 = *(const bf16x8*)&kall[kbase + (size_t)k * A_ + 0];
        bf16x8 k1 = *(const bf16x8*)&kall[kbase + (size_t)k * A_ + 8];
        bf16x8 k2 = *(const bf16x8*)&kall[kbase + (size_t)k * A_ + 16];
        bf16x8 k3 = *(const bf16x8*)&kall[kbase + (size_t)k * A_ + 24];
        float d = 0.f;
#pragma unroll
        for (int i = 0; i < 8; ++i) {
          d += qsh[i]      * (float)k0[i];
          d += qsh[8 + i]  * (float)k1[i];
          d += qsh[16 + i] * (float)k2[i];
          d += qsh[24 + i] * (float)k3[i];
        }
        parr[k] = d;
        lmax = fmaxf(lmax, d);
      }
    }
#pragma unroll
    for (int dlt = 1; dlt < 64; dlt <<= 1) lmax = fmaxf(lmax, __shfl_xor(lmax, dlt));
    if (lane == 0) red[wave] = lmax;
    __syncthreads();
    float bmax = fmaxf(fmaxf(red[0], red[1]), fmaxf(red[2], red[3]));
    float lsum = 0.f;
#pragma unroll 1
    for (int j = 0; j < 9; ++j) {
      int k = tid + j * 256;
      if (k < KREAL) {
        float p = __expf(parr[k] - bmax);
        parr[k] = p;
        lsum += p;
      }
    }
#pragma unroll
    for (int dlt = 1; dlt < 64; dlt <<= 1) lsum += __shfl_xor(lsum, dlt);
    if (lane == 0) red[4 + wave] = lsum;
    __syncthreads();
    float bsum = (red[4] + red[5]) + (red[6] + red[7]);
    int a = tid >> 3, ch = tid & 7;
    const size_t vbase = (size_t)(b * H_ + h) * A_ * KP + (size_t)a * KP;
    float acc = 0.f;
#pragma unroll 1
    for (int j = 0; j < 33; ++j) {
      int kb = ch * 8 + j * 64;
      bf16x8 vv = *(const bf16x8*)&vt[vbase + kb];
      float4 p0 = *(float4*)&parr[kb];
      float4 p1 = *(float4*)&parr[kb + 4];
      acc += p0.x * (float)vv[0] + p0.y * (float)vv[1] + p0.z * (float)vv[2] + p0.w * (float)vv[3];
      acc += p1.x * (float)vv[4] + p1.y * (float)vv[5] + p1.z * (float)vv[6] + p1.w * (float)vv[7];
    }
    opart[a * 9 + ch] = acc;
    __syncthreads();
    if (tid < 32) {
      float t = 0.f;
#pragma unroll
      for (int i = 0; i < 8; ++i) t += opart[tid * 9 + i];
      outc[(size_t)(b * C_ + c) * HA_ + h * A_ + tid] = t / bsum;
    }
  }
}

// ---------------------------------------------------------------------------
// Kernel 3: head projections, raw dual-dtype weights.
// blocks 0..127 seq (MFMA), 128..143 const.
// ---------------------------------------------------------------------------
__global__ __launch_bounds__(256) void hproj_kernel(
    const bf16* __restrict__ outs, const float* __restrict__ outc,
    const void* __restrict__ hws_raw, const void* __restrict__ hwc_raw,
    const unsigned int* __restrict__ x0, void* __restrict__ out)
{
  __shared__ __attribute__((aligned(16))) bf16 wt[64 * 264];   // 33792 B
  __shared__ int sh_cnt;
  bool isf32 = detect_f32(x0, &sh_cnt);
  int bid = blockIdx.x, tid = threadIdx.x;
  if (bid < 128) {
    int b = bid >> 5, s = (bid >> 3) & 3, rc = bid & 7;
    for (int idx = tid; idx < HA_ * E_ / 8; idx += 256) {
      int f = idx >> 3, ec = idx & 7;
      bf16x8 v = ld8(hws_raw, (size_t)s * HA_ * E_ + (size_t)f * E_ + ec * 8, isf32);
#pragma unroll
      for (int j = 0; j < 8; ++j) wt[(ec * 8 + j) * 264 + f] = v[j];
    }
    __syncthreads();
    int lane = tid & 63, wave = tid >> 6, quad = lane >> 4, r = lane & 15;
    int row0 = rc * 64 + wave * 16;
    const size_t xbase = (size_t)(b * S_ + s) * L_ * HA_;
    bf16x8 af[8];
#pragma unroll
    for (int kc = 0; kc < 8; ++kc)
      af[kc] = *(const bf16x8*)&outs[xbase + (size_t)(row0 + r) * HA_ + kc * 32 + quad * 8];
#pragma unroll
    for (int nt = 0; nt < 4; ++nt) {
      f32x4 acc = {0.f,0.f,0.f,0.f};
#pragma unroll
      for (int kc = 0; kc < 8; ++kc) {
        bf16x8 bfr = *(const bf16x8*)&wt[(nt * 16 + r) * 264 + kc * 32 + quad * 8];
        acc = __builtin_amdgcn_mfma_f32_16x16x32_bf16(af[kc], bfr, acc, 0,0,0);
      }
#pragma unroll
      for (int reg = 0; reg < 4; ++reg) {
        int row = row0 + quad * 4 + reg;
        int e = nt * 16 + r;
        size_t oidx = ((size_t)(b * S_ + s) * L_ + row) * E_ + e;
        if (isf32) ((float*)out)[oidx] = acc[reg];
        else       ((bf16*)out)[oidx]  = (bf16)acc[reg];
      }
    }
  } else {
    float* opart = (float*)wt;       // reuse LDS: [4][68]
    int i2 = bid - 128;
    int b = i2 >> 2, c = i2 & 3;
    int fc = tid >> 6, e = tid & 63;
    const float* oc = outc + (size_t)(b * C_ + c) * HA_;
    float acc = 0.f;
#pragma unroll 4
    for (int fo = 0; fo < 64; ++fo) {
      int f = fc * 64 + fo;
      acc += oc[f] * ldf(hwc_raw, ((size_t)c * HA_ + f) * E_ + e, isf32);
    }
    opart[fc * 68 + e] = acc;
    __syncthreads();
    if (tid < 64) {
      float t = (opart[0 * 68 + tid] + opart[1 * 68 + tid]) +
                (opart[2 * 68 + tid] + opart[3 * 68 + tid]);
      size_t oidx = (size_t)B_ * S_ * L_ * E_ + (size_t)(b * C_ + c) * E_ + tid;
      if (isf32) ((float*)out)[oidx] = t;
      else       ((bf16*)out)[oidx]  = (bf16)t;
    }
  }
}

extern "C" void kernel_launch(void* const* d_in, const int* in_sizes, int n_in,
                              void* d_out, int out_size, void* d_ws, size_t ws_size,
                              hipStream_t stream) {
  char* ws = (char*)d_ws;
  bf16* qs    = (bf16*)(ws + OFF_QS);
  bf16* kall  = (bf16*)(ws + OFF_KALL);
  bf16* vt    = (bf16*)(ws + OFF_VT);
  bf16* outs  = (bf16*)(ws + OFF_OUTS);
  float* outc = (float*)(ws + OFF_OUTC);
  const int* maskp = (const int*)d_in[14];
  const unsigned int* x0 = (const unsigned int*)d_in[0];

  proj_kernel<<<384, 256, 0, stream>>>(d_in[0], d_in[1], d_in[2], d_in[4], d_in[5],
                                       d_in[6], d_in[7], d_in[8], d_in[10], d_in[11],
                                       qs, kall, vt);
  attn_kernel<<<1152, 256, 0, stream>>>(qs, kall, vt, maskp, outs,
                                        d_in[3], d_in[9], x0, outc);
  hproj_kernel<<<144, 256, 0, stream>>>(outs, outc, d_in[12], d_in[13], x0, d_out);
}